// Round 9
// baseline (440.472 us; speedup 1.0000x reference)
//
#include <hip/hip_runtime.h>
#include <math.h>

typedef unsigned short u16;
typedef __bf16  bf16x8 __attribute__((ext_vector_type(8)));
typedef float   f32x4  __attribute__((ext_vector_type(4)));

#define SEQ 1024
#define MR  4096          // BATCH*SEQ rows
#define DIP 2192          // in_proj output width
#define DI  1024          // d_inner
#define NH  16
#define CD  1152          // conv dim
#define NCH 32            // chunks per sequence
#define CT  32            // timesteps per chunk
#define NIN (DIP*512)
#define NOUT (512*1024)

__device__ __forceinline__ u16 f2bf(float f) {
  union { float f; unsigned u; } v; v.f = f;
  unsigned r = v.u + 0x7FFFu + ((v.u >> 16) & 1u);
  return (u16)(r >> 16);
}
__device__ __forceinline__ float bf2f(u16 h) {
  union { unsigned u; float f; } v; v.u = ((unsigned)h) << 16; return v.f;
}
__device__ __forceinline__ void splitbf(float v, u16& h, u16& l) {
  h = f2bf(v); l = f2bf(v - bf2f(h));
}
__device__ __forceinline__ float sigm(float x){ return 1.f/(1.f+__expf(-x)); }

// async global->LDS, 16B per lane, dest = wave-uniform base + lane*16
__device__ __forceinline__ void gl16(const u16* g, u16* l) {
  __builtin_amdgcn_global_load_lds((const __attribute__((address_space(1))) void*)g,
                                   (__attribute__((address_space(3))) void*)l,
                                   16, 0, 0);
}

// ---------------- K0: all weights -> (hi,lo) bf16 planes, one launch ----------------
__global__ __launch_bounds__(256) void cast_all(
  const float* __restrict__ f_in, const float* __restrict__ b_in,
  const float* __restrict__ f_out, const float* __restrict__ b_out,
  const float* __restrict__ proj,
  u16* __restrict__ H, u16* __restrict__ L)
{
  int i = blockIdx.x*256 + threadIdx.x;
  constexpr int TOT = 2*NIN + 3*NOUT;
  if (i >= TOT) return;
  float v;
  if (i < NIN)               v = f_in[i];
  else if (i < 2*NIN)        v = b_in[i-NIN];
  else if (i < 2*NIN+NOUT)   v = f_out[i-2*NIN];
  else if (i < 2*NIN+2*NOUT) v = b_out[i-2*NIN-NOUT];
  else                       v = proj[i-2*NIN-2*NOUT];
  u16 hh, ll; splitbf(v, hh, ll);
  H[i] = hh; L[i] = ll;
}

// ---------------- K1: rmsnorm(x) -> hi/lo planes ----------------
__global__ __launch_bounds__(256) void rmsnorm_x(const float* __restrict__ x,
                                                 const float* __restrict__ w,
                                                 u16* __restrict__ hbh,
                                                 u16* __restrict__ hbl){
  int m = blockIdx.x, tid = threadIdx.x;
  const float* xr = x + (size_t)m*512;
  float2 v = *(const float2*)&xr[tid*2];
  float ss = v.x*v.x + v.y*v.y;
  #pragma unroll
  for (int off=32; off; off>>=1) ss += __shfl_xor(ss, off, 64);
  __shared__ float red[4];
  if ((tid&63)==0) red[tid>>6] = ss;
  __syncthreads();
  float total = red[0]+red[1]+red[2]+red[3];
  float rs = rsqrtf(total*(1.f/512.f) + 1e-5f);
  float2 w2 = *(const float2*)&w[tid*2];
  u16 h0,l0,h1,l1;
  splitbf(v.x*rs*w2.x, h0, l0);
  splitbf(v.y*rs*w2.y, h1, l1);
  *(unsigned*)&hbh[(size_t)m*512 + tid*2] = (unsigned)h0 | ((unsigned)h1<<16);
  *(unsigned*)&hbl[(size_t)m*512 + tid*2] = (unsigned)l0 | ((unsigned)l1<<16);
}

// ------- in_proj GEMM: 128x128 tile, split-bf16 planes (round-7 form) -------
__global__ __launch_bounds__(256) void gemm_in(
    const u16* __restrict__ Ah, const u16* __restrict__ Al,
    const u16* __restrict__ Wh, const u16* __restrict__ Wl,
    float* __restrict__ C0)
{
  constexpr int K = 512;
  constexpr int N = DIP;
  __shared__ __align__(16) u16 sAh[128*32];
  __shared__ __align__(16) u16 sAl[128*32];
  __shared__ __align__(16) u16 sBh[128*32];
  __shared__ __align__(16) u16 sBl[128*32];
  const int tid = threadIdx.x;
  const int dir = blockIdx.z;
  const int m0 = blockIdx.x * 128;
  const int n0 = blockIdx.y * 128;
  const int lane = tid & 63;
  const int wid  = tid >> 6;
  const u16* wh_p = Wh + (size_t)dir*NIN;
  const u16* wl_p = Wl + (size_t)dir*NIN;
  const int j0 = wid, j1 = wid + 4;
  const int cp = lane & 3;
  auto goff = [&](int j, bool isB)->size_t {
    int row = 16*j + (lane>>2);
    int s = (row>>1) & 3;
    int kc = (cp ^ s) * 8;
    int grow;
    if (!isB) {
      grow = m0 + row;
      if (dir) grow = (grow & ~1023) + (1023 - (grow & 1023));  // seq flip
    } else {
      grow = n0 + row;
      if (grow >= N) grow = N-1;
    }
    return (size_t)grow*K + kc;
  };
  const size_t a0 = goff(j0,false), a1 = goff(j1,false);
  const size_t b0 = goff(j0,true),  b1 = goff(j1,true);
  const int wm = (wid & 1) * 64;
  const int wn = (wid >> 1) * 64;
  const int quad = lane >> 4;
  const int l16  = lane & 15;
  const int qx = quad ^ ((l16>>1)&3);
  const int baseA = ((wm + l16)*4 + qx)*8;
  const int baseB = ((wn + l16)*4 + qx)*8;
  f32x4 acc[4][4] = {};
  for (int kt = 0; kt < K; kt += 32) {
    __syncthreads();
    gl16(Ah + a0 + kt, &sAh[j0*512]);  gl16(Ah + a1 + kt, &sAh[j1*512]);
    gl16(Al + a0 + kt, &sAl[j0*512]);  gl16(Al + a1 + kt, &sAl[j1*512]);
    gl16(wh_p + b0 + kt, &sBh[j0*512]);  gl16(wh_p + b1 + kt, &sBh[j1*512]);
    gl16(wl_p + b0 + kt, &sBl[j0*512]);  gl16(wl_p + b1 + kt, &sBl[j1*512]);
    __syncthreads();
    bf16x8 ah[4], al[4], bh[4], bl[4];
    #pragma unroll
    for (int i=0;i<4;i++) {
      ah[i] = *(const bf16x8*)&sAh[baseA + i*512];
      al[i] = *(const bf16x8*)&sAl[baseA + i*512];
    }
    #pragma unroll
    for (int j=0;j<4;j++) {
      bh[j] = *(const bf16x8*)&sBh[baseB + j*512];
      bl[j] = *(const bf16x8*)&sBl[baseB + j*512];
    }
    #pragma unroll
    for (int i=0;i<4;i++)
      #pragma unroll
      for (int j=0;j<4;j++) {
        f32x4 t = __builtin_amdgcn_mfma_f32_16x16x32_bf16(ah[i], bl[j], acc[i][j], 0,0,0);
        t       = __builtin_amdgcn_mfma_f32_16x16x32_bf16(al[i], bh[j], t,         0,0,0);
        acc[i][j] = __builtin_amdgcn_mfma_f32_16x16x32_bf16(ah[i], bh[j], t,       0,0,0);
      }
  }
  #pragma unroll
  for (int i=0;i<4;i++)
  #pragma unroll
  for (int j=0;j<4;j++)
  #pragma unroll
  for (int r=0;r<4;r++) {
    int mo = m0 + wm + i*16 + quad*4 + r;
    int no = n0 + wn + j*16 + l16;
    if (no < N) C0[((size_t)dir*MR + mo)*DIP + no] = acc[i][j][r];
  }
}

// ------- out/final GEMM: 64x128 tile (round-7 form) -------
template<int MODE>
__global__ __launch_bounds__(256) void gemm_out(
    const u16* __restrict__ Ah, const u16* __restrict__ Al,
    const u16* __restrict__ Wh, const u16* __restrict__ Wl,
    float* __restrict__ C0, const float* __restrict__ X0,
    u16* __restrict__ C1h, u16* __restrict__ C1l)
{
  constexpr int K = 1024;
  __shared__ __align__(16) u16 sAh[64*32];
  __shared__ __align__(16) u16 sAl[64*32];
  __shared__ __align__(16) u16 sBh[128*32];
  __shared__ __align__(16) u16 sBl[128*32];
  const int tid = threadIdx.x;
  const int dir = blockIdx.z;
  const int m0 = blockIdx.x * 64;
  const int n0 = blockIdx.y * 128;
  const int lane = tid & 63;
  const int wid  = tid >> 6;
  const u16* ah_p = Ah + ((MODE==1) ? (size_t)dir*MR*K : 0);
  const u16* al_p = Al + ((MODE==1) ? (size_t)dir*MR*K : 0);
  const u16* wh_p = Wh + ((MODE==1) ? (size_t)dir*NOUT : 0);
  const u16* wl_p = Wl + ((MODE==1) ? (size_t)dir*NOUT : 0);
  const int cp = lane & 3;
  auto goff = [&](int j, bool isB)->size_t {
    int row = 16*j + (lane>>2);
    int s = (row>>1) & 3;
    int kc = (cp ^ s) * 8;
    int grow = (isB ? n0 : m0) + row;
    return (size_t)grow*K + kc;
  };
  const size_t a0 = goff(wid,false);
  const size_t b0 = goff(wid,true), b1 = goff(wid+4,true);
  const int quad = lane >> 4;
  const int l16  = lane & 15;
  const int qx = quad ^ ((l16>>1)&3);
  const int baseA = (l16*4 + qx)*8;
  const int baseB = ((wid*32 + l16)*4 + qx)*8;
  f32x4 acc[4][2] = {};
  for (int kt = 0; kt < K; kt += 32) {
    __syncthreads();
    gl16(ah_p + a0 + kt, &sAh[wid*512]);
    gl16(al_p + a0 + kt, &sAl[wid*512]);
    gl16(wh_p + b0 + kt, &sBh[wid*512]);  gl16(wh_p + b1 + kt, &sBh[(wid+4)*512]);
    gl16(wl_p + b0 + kt, &sBl[wid*512]);  gl16(wl_p + b1 + kt, &sBl[(wid+4)*512]);
    __syncthreads();
    bf16x8 ah[4], al[4], bh[2], bl[2];
    #pragma unroll
    for (int i=0;i<4;i++) {
      ah[i] = *(const bf16x8*)&sAh[baseA + i*512];
      al[i] = *(const bf16x8*)&sAl[baseA + i*512];
    }
    #pragma unroll
    for (int j=0;j<2;j++) {
      bh[j] = *(const bf16x8*)&sBh[baseB + j*512];
      bl[j] = *(const bf16x8*)&sBl[baseB + j*512];
    }
    #pragma unroll
    for (int i=0;i<4;i++)
      #pragma unroll
      for (int j=0;j<2;j++) {
        f32x4 t = __builtin_amdgcn_mfma_f32_16x16x32_bf16(ah[i], bl[j], acc[i][j], 0,0,0);
        t       = __builtin_amdgcn_mfma_f32_16x16x32_bf16(al[i], bh[j], t,         0,0,0);
        acc[i][j] = __builtin_amdgcn_mfma_f32_16x16x32_bf16(ah[i], bh[j], t,       0,0,0);
      }
  }
  #pragma unroll
  for (int i=0;i<4;i++)
  #pragma unroll
  for (int j=0;j<2;j++)
  #pragma unroll
  for (int r=0;r<4;r++) {
    int mo = m0 + i*16 + quad*4 + r;
    int no = n0 + wid*32 + j*16 + l16;
    float v = acc[i][j][r];
    if (MODE==1) {
      int ro = mo;
      if (dir) ro = (mo & ~1023) + (1023 - (mo & 1023));   // un-flip backward dir
      u16 hh, ll; splitbf(v, hh, ll);
      C1h[(size_t)ro*DI + dir*512 + no] = hh;
      C1l[(size_t)ro*DI + dir*512 + no] = ll;
    } else {
      C0[(size_t)mo*512 + no] = v + X0[(size_t)mo*512 + no];
    }
  }
}

// ---------------- K3: depthwise conv + SiLU + dt softplus (float4) ----------------
__global__ __launch_bounds__(320) void conv_dt(
  const float* __restrict__ Z,
  const float* __restrict__ f_cw, const float* __restrict__ f_cb,
  const float* __restrict__ b_cw, const float* __restrict__ b_cb,
  const float* __restrict__ f_dtb, const float* __restrict__ b_dtb,
  float* __restrict__ xconv,
  float* __restrict__ Bc, float* __restrict__ Cc,
  float* __restrict__ dtq)
{
  int bm = blockIdx.x;             // dirb*1024 + t
  int dir = bm >> 12;
  int t = bm & 1023;
  const float* cw  = dir ? b_cw : f_cw;
  const float* cb  = dir ? b_cb : f_cb;
  const float* dtb = dir ? b_dtb : f_dtb;
  int tid = threadIdx.x;
  if (tid < 288) {
    int c0 = tid*4;
    const float* zbase = Z + (size_t)(bm-3)*DIP + 1024 + c0;
    float4 w0 = *(const float4*)&cw[c0*4];
    float4 w1 = *(const float4*)&cw[(c0+1)*4];
    float4 w2 = *(const float4*)&cw[(c0+2)*4];
    float4 w3 = *(const float4*)&cw[(c0+3)*4];
    float4 z0 = {0,0,0,0}, z1 = {0,0,0,0}, z2 = {0,0,0,0};
    float4 z3 = *(const float4*)(zbase + 3*(size_t)DIP);
    if (t >= 3) {
      z0 = *(const float4*)(zbase);
      z1 = *(const float4*)(zbase + (size_t)DIP);
      z2 = *(const float4*)(zbase + 2*(size_t)DIP);
    } else {
      if (t >= 1) z2 = *(const float4*)(zbase + 2*(size_t)DIP);
      if (t >= 2) z1 = *(const float4*)(zbase + (size_t)DIP);
    }
    float4 a = *(const float4*)&cb[c0];
    a.x += z0.x*w0.x + z1.x*w0.y + z2.x*w0.z + z3.x*w0.w;
    a.y += z0.y*w1.x + z1.y*w1.y + z2.y*w1.z + z3.y*w1.w;
    a.z += z0.z*w2.x + z1.z*w2.y + z2.z*w2.z + z3.z*w2.w;
    a.w += z0.w*w3.x + z1.w*w3.y + z2.w*w3.z + z3.w*w3.w;
    float4 v;
    v.x = a.x * sigm(a.x); v.y = a.y * sigm(a.y);
    v.z = a.z * sigm(a.z); v.w = a.w * sigm(a.w);
    if (c0 < 1024)      *(float4*)&xconv[(size_t)bm*DI + c0] = v;
    else if (c0 < 1088) *(float4*)&Bc[(size_t)bm*64 + (c0-1024)] = v;
    else                *(float4*)&Cc[(size_t)bm*64 + (c0-1088)] = v;
  }
  if (tid < NH) {
    float dtraw = Z[(size_t)bm*DIP + 2176 + tid] + dtb[tid];
    float dt = (dtraw > 20.f) ? dtraw : log1pf(__expf(dtraw));
    dtq[(size_t)bm*NH + tid] = dt;
  }
}

// ---------- K4a: chunked local scan, lane=p, 1 head/wave, T=32 ----------
// B/C read DIRECTLY from global with wave-uniform addresses -> backend
// scalarizes to s_load (SMEM pipe), freeing the LDS/VALU pipes. No LDS.
__global__ __launch_bounds__(256) void scan_chunk(
  const float* __restrict__ dtq, const float* __restrict__ xconv,
  const float* __restrict__ Bc, const float* __restrict__ Cc,
  const float* __restrict__ f_Al, const float* __restrict__ b_Al,
  float* __restrict__ yraw, float* __restrict__ cumdec, float* __restrict__ S)
{
  int bx = blockIdx.x;
  int hq = bx & 3, chunk = (bx>>2)&(NCH-1), dirb = bx>>7;
  int w = threadIdx.x >> 6, lane = threadIdx.x & 63;
  int h = hq*4 + w;
  int base_row = dirb*1024 + chunk*CT;
  const float* Bg = Bc + (size_t)base_row*64;
  const float* Cg = Cc + (size_t)base_row*64;
  const float* Al = (dirb >= 4) ? b_Al : f_Al;
  float A = -__expf(Al[h]);
  float hs[64];
  #pragma unroll
  for (int n=0;n<64;n++) hs[n]=0.f;
  float cd = 1.f;
  const float* dt_p = dtq   + (size_t)base_row*16 + h;
  const float* x_p  = xconv + (size_t)base_row*1024 + h*64 + lane;
  float*       y_p  = yraw  + (size_t)base_row*1024 + h*64 + lane;
  float*       cd_p = cumdec+ (size_t)base_row*16 + h;
  for (int j=0;j<CT;j++) {
    float dt = dt_p[j*16];                // wave-uniform
    float x  = x_p[(size_t)j*1024];       // coalesced over lanes
    float dec = __expf(dt*A);
    float dx = dt*x;
    cd *= dec;
    float y0 = 0.f, y1 = 0.f, y2 = 0.f, y3 = 0.f;
    #pragma unroll
    for (int n4=0;n4<16;n4++) {
      float4 b4 = *(const float4*)&Bg[j*64 + n4*4];  // uniform -> s_load
      float4 c4 = *(const float4*)&Cg[j*64 + n4*4];  // uniform -> s_load
      hs[n4*4+0] = fmaf(hs[n4*4+0], dec, dx*b4.x); y0 = fmaf(hs[n4*4+0], c4.x, y0);
      hs[n4*4+1] = fmaf(hs[n4*4+1], dec, dx*b4.y); y1 = fmaf(hs[n4*4+1], c4.y, y1);
      hs[n4*4+2] = fmaf(hs[n4*4+2], dec, dx*b4.z); y2 = fmaf(hs[n4*4+2], c4.z, y2);
      hs[n4*4+3] = fmaf(hs[n4*4+3], dec, dx*b4.w); y3 = fmaf(hs[n4*4+3], c4.w, y3);
    }
    y_p[(size_t)j*1024] = (y0+y1) + (y2+y3);
    if (lane == 0) cd_p[j*16] = cd;
  }
  size_t inst = ((size_t)(dirb*16+h)*NCH + chunk)*4096;
  #pragma unroll
  for (int n=0;n<64;n++) S[inst + n*64 + lane] = hs[n];
}

// ---------- K4b: inter-chunk combine; S[c] overwritten in-place with h_start(c) ----------
__global__ __launch_bounds__(256) void scan_comb(
  const float* __restrict__ cumdec, float* __restrict__ S)
{
  int ih = blockIdx.x >> 4;            // dirb*16 + h
  int sub = blockIdx.x & 15;
  int dirb = ih >> 4, h = ih & 15;
  int elem = sub*256 + threadIdx.x;    // 0..4095 = n*64+p
  size_t base = (size_t)ih*NCH*4096 + elem;
  float hr = 0.f;
  for (int c=0;c<NCH;c++) {
    float P = cumdec[((size_t)(dirb*1024 + c*CT + CT-1))*16 + h];
    float s = S[base + c*4096];
    S[base + c*4096] = hr;             // h_start for chunk c
    hr = fmaf(hr, P, s);
  }
}

// ---------- K4c: correction y += cumdec * (C_t . h_start), uniform C via s_load ----------
__global__ __launch_bounds__(256) void scan_fix(
  const float* __restrict__ Cc, const float* __restrict__ cumdec,
  const float* __restrict__ S, float* __restrict__ yraw)
{
  int bx = blockIdx.x;
  int hq = bx & 3, chunk = (bx>>2)&(NCH-1), dirb = bx>>7;
  if (chunk == 0) return;               // h_start = 0, block-uniform exit
  int w = threadIdx.x >> 6, lane = threadIdx.x & 63;
  int h = hq*4 + w;
  int row0 = dirb*1024 + chunk*CT;
  const float* Cg = Cc + (size_t)row0*64;
  size_t inst = ((size_t)(dirb*16+h)*NCH + chunk)*4096;
  float hv[64];
  #pragma unroll
  for (int n=0;n<64;n++) hv[n] = S[inst + n*64 + lane];   // h_start[p=lane][n]
  const float* cd_p = cumdec + (size_t)row0*16 + h;
  float* y_p = yraw + (size_t)row0*1024 + h*64 + lane;
  for (int j=0;j<CT;j++) {
    float cdj = cd_p[j*16];
    float y0 = 0.f, y1 = 0.f, y2 = 0.f, y3 = 0.f;
    #pragma unroll
    for (int n4=0;n4<16;n4++) {
      float4 c4 = *(const float4*)&Cg[j*64 + n4*4];   // uniform -> s_load
      y0 = fmaf(hv[n4*4+0], c4.x, y0);
      y1 = fmaf(hv[n4*4+1], c4.y, y1);
      y2 = fmaf(hv[n4*4+2], c4.z, y2);
      y3 = fmaf(hv[n4*4+3], c4.w, y3);
    }
    y_p[(size_t)j*1024] += cdj * ((y0+y1) + (y2+y3));
  }
}

// ---------------- K5: +x*D, gate silu(z), rmsnorm -> yg hi/lo planes (float4) ----------------
__global__ __launch_bounds__(256) void gate_norm(
  const float* __restrict__ yraw, const float* __restrict__ xconv,
  const float* __restrict__ Z,
  const float* __restrict__ f_D, const float* __restrict__ b_D,
  const float* __restrict__ f_gw, const float* __restrict__ b_gw,
  u16* __restrict__ ygh, u16* __restrict__ ygl)
{
  int bm = blockIdx.x, tid = threadIdx.x;
  int dir = bm >> 12;
  const float* Dp = dir ? b_D : f_D;
  const float* gw = dir ? b_gw : f_gw;
  int c0 = tid*4;
  float4 y4 = *(const float4*)&yraw [(size_t)bm*DI + c0];
  float4 x4 = *(const float4*)&xconv[(size_t)bm*DI + c0];
  float4 z4 = *(const float4*)&Z[(size_t)bm*DIP + c0];   // z = cols 0..1023
  float Dv = Dp[c0>>6];
  float4 v;
  v.x = (y4.x + x4.x*Dv) * (z4.x * sigm(z4.x));
  v.y = (y4.y + x4.y*Dv) * (z4.y * sigm(z4.y));
  v.z = (y4.z + x4.z*Dv) * (z4.z * sigm(z4.z));
  v.w = (y4.w + x4.w*Dv) * (z4.w * sigm(z4.w));
  float ss = v.x*v.x + v.y*v.y + v.z*v.z + v.w*v.w;
  #pragma unroll
  for (int off=32; off; off>>=1) ss += __shfl_xor(ss, off, 64);
  __shared__ float red[4];
  if ((tid&63)==0) red[tid>>6] = ss;
  __syncthreads();
  float total = red[0]+red[1]+red[2]+red[3];
  float rs = rsqrtf(total*(1.f/1024.f) + 1e-5f);
  float4 g4 = *(const float4*)&gw[c0];
  ushort4 hh, ll;
  splitbf(v.x*rs*g4.x, hh.x, ll.x);
  splitbf(v.y*rs*g4.y, hh.y, ll.y);
  splitbf(v.z*rs*g4.z, hh.z, ll.z);
  splitbf(v.w*rs*g4.w, hh.w, ll.w);
  *(ushort4*)&ygh[(size_t)bm*DI + c0] = hh;
  *(ushort4*)&ygl[(size_t)bm*DI + c0] = ll;
}

extern "C" void kernel_launch(void* const* d_in, const int* in_sizes, int n_in,
                              void* d_out, int out_size, void* d_ws, size_t ws_size,
                              hipStream_t stream)
{
  const float* x        = (const float*)d_in[0];
  const float* norm_w   = (const float*)d_in[1];
  const float* f_in_w   = (const float*)d_in[2];
  const float* f_conv_w = (const float*)d_in[3];
  const float* f_conv_b = (const float*)d_in[4];
  const float* f_dt_bias= (const float*)d_in[5];
  const float* f_A_log  = (const float*)d_in[6];
  const float* f_D      = (const float*)d_in[7];
  const float* f_gw     = (const float*)d_in[8];
  const float* f_out_w  = (const float*)d_in[9];
  const float* b_in_w   = (const float*)d_in[10];
  const float* b_conv_w = (const float*)d_in[11];
  const float* b_conv_b = (const float*)d_in[12];
  const float* b_dt_bias= (const float*)d_in[13];
  const float* b_A_log  = (const float*)d_in[14];
  const float* b_D      = (const float*)d_in[15];
  const float* b_gw     = (const float*)d_in[16];
  const float* b_out_w  = (const float*)d_in[17];
  const float* proj_w   = (const float*)d_in[18];

  char* ws = (char*)d_ws;
  size_t off = 0;
  auto alloc = [&](size_t bytes)->char* {
    char* p = ws + off; off = (off + bytes + 255) & ~(size_t)255; return p;
  };
  constexpr size_t WTOT = 2*(size_t)NIN + 3*(size_t)NOUT;   // 3,817,472
  u16*   hbh   = (u16*)  alloc((size_t)MR*512*2);        //  4.2 MB
  u16*   hbl   = (u16*)  alloc((size_t)MR*512*2);        //  4.2 MB
  u16*   wH    = (u16*)  alloc(WTOT*2);                  //  7.6 MB
  u16*   wL    = (u16*)  alloc(WTOT*2);                  //  7.6 MB
  float* Z     = (float*)alloc(2*(size_t)MR*DIP*4);      // 71.8 MB
  float* xconv = (float*)alloc(2*(size_t)MR*DI*4);       // 33.6 MB
  float* Bc    = (float*)alloc(2*(size_t)MR*64*4);       //  2.1 MB
  float* Cc    = (float*)alloc(2*(size_t)MR*64*4);       //  2.1 MB
  float* dtq   = (float*)alloc(2*(size_t)MR*NH*4);       //  0.5 MB
  float* cumdec= (float*)alloc(2*(size_t)MR*NH*4);       //  0.5 MB
  float* S     = (float*)alloc((size_t)4096*4096*4);     // 67.1 MB
  float* yraw  = (float*)alloc(2*(size_t)MR*DI*4);       // 33.6 MB
  // weight plane views
  u16* wih = wH;                   u16* wil = wL;
  u16* woh = wH + 2*(size_t)NIN;   u16* wol = wL + 2*(size_t)NIN;
  u16* wph = woh + 2*(size_t)NOUT; u16* wpl = wol + 2*(size_t)NOUT;
  // alias late-stage planes into S (dead after scan_fix):
  u16* ycath = (u16*)((char*)S);
  u16* ycatl = (u16*)((char*)S + ((size_t)MR*DI*2));
  u16* ygh   = (u16*)((char*)S + 2*((size_t)MR*DI*2));
  u16* ygl   = (u16*)((char*)S + 4*((size_t)MR*DI*2));

  cast_all<<<(int)((WTOT+255)/256),256,0,stream>>>(f_in_w, b_in_w, f_out_w, b_out_w, proj_w, wH, wL);

  rmsnorm_x<<<MR,256,0,stream>>>(x, norm_w, hbh, hbl);
  gemm_in<<<dim3(32,18,2),256,0,stream>>>(hbh, hbl, wih, wil, Z);
  conv_dt<<<2*MR,320,0,stream>>>(Z, f_conv_w, f_conv_b, b_conv_w, b_conv_b,
                                 f_dt_bias, b_dt_bias, xconv, Bc, Cc, dtq);
  scan_chunk<<<1024,256,0,stream>>>(dtq, xconv, Bc, Cc, f_A_log, b_A_log,
                                    yraw, cumdec, S);
  scan_comb<<<2048,256,0,stream>>>(cumdec, S);
  scan_fix<<<1024,256,0,stream>>>(Cc, cumdec, S, yraw);
  gate_norm<<<2*MR,256,0,stream>>>(yraw, xconv, Z, f_D, b_D, f_gw, b_gw, ygh, ygl);
  gemm_out<1><<<dim3(64,4,2),256,0,stream>>>(ygh, ygl, woh, wol, nullptr, nullptr, ycath, ycatl);
  gemm_out<2><<<dim3(64,4,1),256,0,stream>>>(ycath, ycatl, wph, wpl, (float*)d_out, x, nullptr, nullptr);
}

// Round 10
// 372.543 us; speedup vs baseline: 1.1823x; 1.1823x over previous
//
#include <hip/hip_runtime.h>
#include <math.h>

typedef unsigned short u16;
typedef __bf16  bf16x8 __attribute__((ext_vector_type(8)));
typedef float   f32x4  __attribute__((ext_vector_type(4)));
typedef unsigned short u16x8 __attribute__((ext_vector_type(8)));

#define SEQ 1024
#define MR  4096          // BATCH*SEQ rows
#define DIP 2192          // in_proj output width
#define DI  1024          // d_inner
#define NH  16
#define CD  1152          // conv dim
#define NCH 32            // chunks per sequence
#define CT  32            // timesteps per chunk
#define NIN (DIP*512)
#define NOUT (512*1024)

__device__ __forceinline__ u16 f2bf(float f) {
  union { float f; unsigned u; } v; v.f = f;
  unsigned r = v.u + 0x7FFFu + ((v.u >> 16) & 1u);
  return (u16)(r >> 16);
}
__device__ __forceinline__ float bf2f(u16 h) {
  union { unsigned u; float f; } v; v.u = ((unsigned)h) << 16; return v.f;
}
__device__ __forceinline__ void splitbf(float v, u16& h, u16& l) {
  h = f2bf(v); l = f2bf(v - bf2f(h));
}
__device__ __forceinline__ float sigm(float x){ return 1.f/(1.f+__expf(-x)); }

// split 8 contiguous fp32 -> hi/lo bf16x8 fragments
__device__ __forceinline__ void split8(const float* p, bf16x8& H, bf16x8& L) {
  float4 a = *(const float4*)p, b = *(const float4*)(p+4);
  u16x8 hu, lu; u16 hh, ll;
  splitbf(a.x,hh,ll); hu[0]=hh; lu[0]=ll;
  splitbf(a.y,hh,ll); hu[1]=hh; lu[1]=ll;
  splitbf(a.z,hh,ll); hu[2]=hh; lu[2]=ll;
  splitbf(a.w,hh,ll); hu[3]=hh; lu[3]=ll;
  splitbf(b.x,hh,ll); hu[4]=hh; lu[4]=ll;
  splitbf(b.y,hh,ll); hu[5]=hh; lu[5]=ll;
  splitbf(b.z,hh,ll); hu[6]=hh; lu[6]=ll;
  splitbf(b.w,hh,ll); hu[7]=hh; lu[7]=ll;
  H = __builtin_bit_cast(bf16x8, hu);
  L = __builtin_bit_cast(bf16x8, lu);
}
// split 8 strided fp32 -> hi/lo bf16x8
__device__ __forceinline__ void split8s(const float* p, int stride, bf16x8& H, bf16x8& L) {
  u16x8 hu, lu; u16 hh, ll;
  #pragma unroll
  for (int jj=0;jj<8;jj++){ splitbf(p[(size_t)jj*stride], hh, ll); hu[jj]=hh; lu[jj]=ll; }
  H = __builtin_bit_cast(bf16x8, hu);
  L = __builtin_bit_cast(bf16x8, lu);
}

// async global->LDS, 16B per lane
__device__ __forceinline__ void gl16(const u16* g, u16* l) {
  __builtin_amdgcn_global_load_lds((const __attribute__((address_space(1))) void*)g,
                                   (__attribute__((address_space(3))) void*)l,
                                   16, 0, 0);
}

// ---------------- K0: all weights -> (hi,lo) bf16 planes ----------------
__global__ __launch_bounds__(256) void cast_all(
  const float* __restrict__ f_in, const float* __restrict__ b_in,
  const float* __restrict__ f_out, const float* __restrict__ b_out,
  const float* __restrict__ proj,
  u16* __restrict__ H, u16* __restrict__ L)
{
  int i = blockIdx.x*256 + threadIdx.x;
  constexpr int TOT = 2*NIN + 3*NOUT;
  if (i >= TOT) return;
  float v;
  if (i < NIN)               v = f_in[i];
  else if (i < 2*NIN)        v = b_in[i-NIN];
  else if (i < 2*NIN+NOUT)   v = f_out[i-2*NIN];
  else if (i < 2*NIN+2*NOUT) v = b_out[i-2*NIN-NOUT];
  else                       v = proj[i-2*NIN-2*NOUT];
  u16 hh, ll; splitbf(v, hh, ll);
  H[i] = hh; L[i] = ll;
}

// ---------------- K1: rmsnorm(x) -> hi/lo planes ----------------
__global__ __launch_bounds__(256) void rmsnorm_x(const float* __restrict__ x,
                                                 const float* __restrict__ w,
                                                 u16* __restrict__ hbh,
                                                 u16* __restrict__ hbl){
  int m = blockIdx.x, tid = threadIdx.x;
  const float* xr = x + (size_t)m*512;
  float2 v = *(const float2*)&xr[tid*2];
  float ss = v.x*v.x + v.y*v.y;
  #pragma unroll
  for (int off=32; off; off>>=1) ss += __shfl_xor(ss, off, 64);
  __shared__ float red[4];
  if ((tid&63)==0) red[tid>>6] = ss;
  __syncthreads();
  float total = red[0]+red[1]+red[2]+red[3];
  float rs = rsqrtf(total*(1.f/512.f) + 1e-5f);
  float2 w2 = *(const float2*)&w[tid*2];
  u16 h0,l0,h1,l1;
  splitbf(v.x*rs*w2.x, h0, l0);
  splitbf(v.y*rs*w2.y, h1, l1);
  *(unsigned*)&hbh[(size_t)m*512 + tid*2] = (unsigned)h0 | ((unsigned)h1<<16);
  *(unsigned*)&hbl[(size_t)m*512 + tid*2] = (unsigned)l0 | ((unsigned)l1<<16);
}

// ------- in_proj GEMM: 128x128 tile (round-7 form) -------
__global__ __launch_bounds__(256) void gemm_in(
    const u16* __restrict__ Ah, const u16* __restrict__ Al,
    const u16* __restrict__ Wh, const u16* __restrict__ Wl,
    float* __restrict__ C0)
{
  constexpr int K = 512;
  constexpr int N = DIP;
  __shared__ __align__(16) u16 sAh[128*32];
  __shared__ __align__(16) u16 sAl[128*32];
  __shared__ __align__(16) u16 sBh[128*32];
  __shared__ __align__(16) u16 sBl[128*32];
  const int tid = threadIdx.x;
  const int dir = blockIdx.z;
  const int m0 = blockIdx.x * 128;
  const int n0 = blockIdx.y * 128;
  const int lane = tid & 63;
  const int wid  = tid >> 6;
  const u16* wh_p = Wh + (size_t)dir*NIN;
  const u16* wl_p = Wl + (size_t)dir*NIN;
  const int j0 = wid, j1 = wid + 4;
  const int cp = lane & 3;
  auto goff = [&](int j, bool isB)->size_t {
    int row = 16*j + (lane>>2);
    int s = (row>>1) & 3;
    int kc = (cp ^ s) * 8;
    int grow;
    if (!isB) {
      grow = m0 + row;
      if (dir) grow = (grow & ~1023) + (1023 - (grow & 1023));  // seq flip
    } else {
      grow = n0 + row;
      if (grow >= N) grow = N-1;
    }
    return (size_t)grow*K + kc;
  };
  const size_t a0 = goff(j0,false), a1 = goff(j1,false);
  const size_t b0 = goff(j0,true),  b1 = goff(j1,true);
  const int wm = (wid & 1) * 64;
  const int wn = (wid >> 1) * 64;
  const int quad = lane >> 4;
  const int l16  = lane & 15;
  const int qx = quad ^ ((l16>>1)&3);
  const int baseA = ((wm + l16)*4 + qx)*8;
  const int baseB = ((wn + l16)*4 + qx)*8;
  f32x4 acc[4][4] = {};
  for (int kt = 0; kt < K; kt += 32) {
    __syncthreads();
    gl16(Ah + a0 + kt, &sAh[j0*512]);  gl16(Ah + a1 + kt, &sAh[j1*512]);
    gl16(Al + a0 + kt, &sAl[j0*512]);  gl16(Al + a1 + kt, &sAl[j1*512]);
    gl16(wh_p + b0 + kt, &sBh[j0*512]);  gl16(wh_p + b1 + kt, &sBh[j1*512]);
    gl16(wl_p + b0 + kt, &sBl[j0*512]);  gl16(wl_p + b1 + kt, &sBl[j1*512]);
    __syncthreads();
    bf16x8 ah[4], al[4], bh[4], bl[4];
    #pragma unroll
    for (int i=0;i<4;i++) {
      ah[i] = *(const bf16x8*)&sAh[baseA + i*512];
      al[i] = *(const bf16x8*)&sAl[baseA + i*512];
    }
    #pragma unroll
    for (int j=0;j<4;j++) {
      bh[j] = *(const bf16x8*)&sBh[baseB + j*512];
      bl[j] = *(const bf16x8*)&sBl[baseB + j*512];
    }
    #pragma unroll
    for (int i=0;i<4;i++)
      #pragma unroll
      for (int j=0;j<4;j++) {
        f32x4 t = __builtin_amdgcn_mfma_f32_16x16x32_bf16(ah[i], bl[j], acc[i][j], 0,0,0);
        t       = __builtin_amdgcn_mfma_f32_16x16x32_bf16(al[i], bh[j], t,         0,0,0);
        acc[i][j] = __builtin_amdgcn_mfma_f32_16x16x32_bf16(ah[i], bh[j], t,       0,0,0);
      }
  }
  #pragma unroll
  for (int i=0;i<4;i++)
  #pragma unroll
  for (int j=0;j<4;j++)
  #pragma unroll
  for (int r=0;r<4;r++) {
    int mo = m0 + wm + i*16 + quad*4 + r;
    int no = n0 + wn + j*16 + l16;
    if (no < N) C0[((size_t)dir*MR + mo)*DIP + no] = acc[i][j][r];
  }
}

// ------- out/final GEMM: 64x128 tile (round-7 form) -------
template<int MODE>
__global__ __launch_bounds__(256) void gemm_out(
    const u16* __restrict__ Ah, const u16* __restrict__ Al,
    const u16* __restrict__ Wh, const u16* __restrict__ Wl,
    float* __restrict__ C0, const float* __restrict__ X0,
    u16* __restrict__ C1h, u16* __restrict__ C1l)
{
  constexpr int K = 1024;
  __shared__ __align__(16) u16 sAh[64*32];
  __shared__ __align__(16) u16 sAl[64*32];
  __shared__ __align__(16) u16 sBh[128*32];
  __shared__ __align__(16) u16 sBl[128*32];
  const int tid = threadIdx.x;
  const int dir = blockIdx.z;
  const int m0 = blockIdx.x * 64;
  const int n0 = blockIdx.y * 128;
  const int lane = tid & 63;
  const int wid  = tid >> 6;
  const u16* ah_p = Ah + ((MODE==1) ? (size_t)dir*MR*K : 0);
  const u16* al_p = Al + ((MODE==1) ? (size_t)dir*MR*K : 0);
  const u16* wh_p = Wh + ((MODE==1) ? (size_t)dir*NOUT : 0);
  const u16* wl_p = Wl + ((MODE==1) ? (size_t)dir*NOUT : 0);
  const int cp = lane & 3;
  auto goff = [&](int j, bool isB)->size_t {
    int row = 16*j + (lane>>2);
    int s = (row>>1) & 3;
    int kc = (cp ^ s) * 8;
    int grow = (isB ? n0 : m0) + row;
    return (size_t)grow*K + kc;
  };
  const size_t a0 = goff(wid,false);
  const size_t b0 = goff(wid,true), b1 = goff(wid+4,true);
  const int quad = lane >> 4;
  const int l16  = lane & 15;
  const int qx = quad ^ ((l16>>1)&3);
  const int baseA = (l16*4 + qx)*8;
  const int baseB = ((wid*32 + l16)*4 + qx)*8;
  f32x4 acc[4][2] = {};
  for (int kt = 0; kt < K; kt += 32) {
    __syncthreads();
    gl16(ah_p + a0 + kt, &sAh[wid*512]);
    gl16(al_p + a0 + kt, &sAl[wid*512]);
    gl16(wh_p + b0 + kt, &sBh[wid*512]);  gl16(wh_p + b1 + kt, &sBh[(wid+4)*512]);
    gl16(wl_p + b0 + kt, &sBl[wid*512]);  gl16(wl_p + b1 + kt, &sBl[(wid+4)*512]);
    __syncthreads();
    bf16x8 ah[4], al[4], bh[2], bl[2];
    #pragma unroll
    for (int i=0;i<4;i++) {
      ah[i] = *(const bf16x8*)&sAh[baseA + i*512];
      al[i] = *(const bf16x8*)&sAl[baseA + i*512];
    }
    #pragma unroll
    for (int j=0;j<2;j++) {
      bh[j] = *(const bf16x8*)&sBh[baseB + j*512];
      bl[j] = *(const bf16x8*)&sBl[baseB + j*512];
    }
    #pragma unroll
    for (int i=0;i<4;i++)
      #pragma unroll
      for (int j=0;j<2;j++) {
        f32x4 t = __builtin_amdgcn_mfma_f32_16x16x32_bf16(ah[i], bl[j], acc[i][j], 0,0,0);
        t       = __builtin_amdgcn_mfma_f32_16x16x32_bf16(al[i], bh[j], t,         0,0,0);
        acc[i][j] = __builtin_amdgcn_mfma_f32_16x16x32_bf16(ah[i], bh[j], t,       0,0,0);
      }
  }
  #pragma unroll
  for (int i=0;i<4;i++)
  #pragma unroll
  for (int j=0;j<2;j++)
  #pragma unroll
  for (int r=0;r<4;r++) {
    int mo = m0 + i*16 + quad*4 + r;
    int no = n0 + wid*32 + j*16 + l16;
    float v = acc[i][j][r];
    if (MODE==1) {
      int ro = mo;
      if (dir) ro = (mo & ~1023) + (1023 - (mo & 1023));   // un-flip backward dir
      u16 hh, ll; splitbf(v, hh, ll);
      C1h[(size_t)ro*DI + dir*512 + no] = hh;
      C1l[(size_t)ro*DI + dir*512 + no] = ll;
    } else {
      C0[(size_t)mo*512 + no] = v + X0[(size_t)mo*512 + no];
    }
  }
}

// ---------------- K3: depthwise conv + SiLU + dt softplus (float4) ----------------
__global__ __launch_bounds__(320) void conv_dt(
  const float* __restrict__ Z,
  const float* __restrict__ f_cw, const float* __restrict__ f_cb,
  const float* __restrict__ b_cw, const float* __restrict__ b_cb,
  const float* __restrict__ f_dtb, const float* __restrict__ b_dtb,
  float* __restrict__ xconv,
  float* __restrict__ Bc, float* __restrict__ Cc,
  float* __restrict__ dtq)
{
  int bm = blockIdx.x;             // dirb*1024 + t
  int dir = bm >> 12;
  int t = bm & 1023;
  const float* cw  = dir ? b_cw : f_cw;
  const float* cb  = dir ? b_cb : f_cb;
  const float* dtb = dir ? b_dtb : f_dtb;
  int tid = threadIdx.x;
  if (tid < 288) {
    int c0 = tid*4;
    const float* zbase = Z + (size_t)(bm-3)*DIP + 1024 + c0;
    float4 w0 = *(const float4*)&cw[c0*4];
    float4 w1 = *(const float4*)&cw[(c0+1)*4];
    float4 w2 = *(const float4*)&cw[(c0+2)*4];
    float4 w3 = *(const float4*)&cw[(c0+3)*4];
    float4 z0 = {0,0,0,0}, z1 = {0,0,0,0}, z2 = {0,0,0,0};
    float4 z3 = *(const float4*)(zbase + 3*(size_t)DIP);
    if (t >= 3) {
      z0 = *(const float4*)(zbase);
      z1 = *(const float4*)(zbase + (size_t)DIP);
      z2 = *(const float4*)(zbase + 2*(size_t)DIP);
    } else {
      if (t >= 1) z2 = *(const float4*)(zbase + 2*(size_t)DIP);
      if (t >= 2) z1 = *(const float4*)(zbase + (size_t)DIP);
    }
    float4 a = *(const float4*)&cb[c0];
    a.x += z0.x*w0.x + z1.x*w0.y + z2.x*w0.z + z3.x*w0.w;
    a.y += z0.y*w1.x + z1.y*w1.y + z2.y*w1.z + z3.y*w1.w;
    a.z += z0.z*w2.x + z1.z*w2.y + z2.z*w2.z + z3.z*w2.w;
    a.w += z0.w*w3.x + z1.w*w3.y + z2.w*w3.z + z3.w*w3.w;
    float4 v;
    v.x = a.x * sigm(a.x); v.y = a.y * sigm(a.y);
    v.z = a.z * sigm(a.z); v.w = a.w * sigm(a.w);
    if (c0 < 1024)      *(float4*)&xconv[(size_t)bm*DI + c0] = v;
    else if (c0 < 1088) *(float4*)&Bc[(size_t)bm*64 + (c0-1024)] = v;
    else                *(float4*)&Cc[(size_t)bm*64 + (c0-1088)] = v;
  }
  if (tid < NH) {
    float dtraw = Z[(size_t)bm*DIP + 2176 + tid] + dtb[tid];
    float dt = (dtraw > 20.f) ? dtraw : log1pf(__expf(dtraw));
    dtq[(size_t)bm*NH + tid] = dt;
  }
}

// ---------- K4a: MFMA chunk scan ----------
// block = (dirb 8, chunk 32, hq 4), wave w = head hq*4+w. Per wave:
//  G = C @ B^T (32x32, K=64); M[t,s] = (s<=t) exp(A(ct_t-ct_s)) dt_s G[t,s];
//  Y1 = M @ X^T-frags (t,p);  S^T[p,n] = sum_s X[s,p] w_s B[s,n].
// All operands split-bf16; M round-trips C/D->A layout via 5KB/wave LDS.
__global__ __launch_bounds__(256) void scan_mfma(
  const float* __restrict__ dtq, const float* __restrict__ xconv,
  const float* __restrict__ Bc, const float* __restrict__ Cc,
  const float* __restrict__ f_Al, const float* __restrict__ b_Al,
  float* __restrict__ yraw, float* __restrict__ cumdec, float* __restrict__ S)
{
  __shared__ __align__(16) u16 sMh[4][32*40];
  __shared__ __align__(16) u16 sMl[4][32*40];
  __shared__ float scum[4][32];
  __shared__ float sdt[4][32];
  int bx = blockIdx.x;
  int hq = bx & 3, chunk = (bx>>2)&(NCH-1), dirb = bx>>7;
  int w = threadIdx.x >> 6, lane = threadIdx.x & 63;
  int h = hq*4 + w;
  int base_row = dirb*1024 + chunk*CT;
  const int quad = lane >> 4, l16 = lane & 15;
  const float* Al = (dirb >= 4) ? b_Al : f_Al;
  float A = -__expf(Al[h]);
  // dt + inclusive prefix over 32 timesteps (lanes 0..31)
  float dtl = 0.f, cum = 0.f;
  if (lane < 32) { dtl = dtq[(size_t)(base_row + lane)*16 + h]; cum = dtl; }
  #pragma unroll
  for (int off=1; off<32; off<<=1) {
    int src = (lane >= off) ? lane-off : lane;
    float o = __shfl(cum, src);
    if (lane >= off && lane < 32) cum += o;
  }
  if (lane < 32) {
    sdt[w][lane]  = dtl;
    scum[w][lane] = cum;
    cumdec[(size_t)(base_row + lane)*16 + h] = __expf(A*cum);
  }
  // ---- G = C @ B^T ----
  bf16x8 chf[2][2], clf[2][2], bhf[2][2], blf[2][2];
  #pragma unroll
  for (int i=0;i<2;i++)
  #pragma unroll
  for (int kk=0;kk<2;kk++) {
    split8(Cc + (size_t)(base_row + 16*i + l16)*64 + kk*32 + quad*8, chf[i][kk], clf[i][kk]);
    split8(Bc + (size_t)(base_row + 16*i + l16)*64 + kk*32 + quad*8, bhf[i][kk], blf[i][kk]);
  }
  f32x4 g[2][2];
  #pragma unroll
  for (int i=0;i<2;i++)
  #pragma unroll
  for (int j=0;j<2;j++) {
    f32x4 acc = {};
    #pragma unroll
    for (int kk=0;kk<2;kk++) {
      acc = __builtin_amdgcn_mfma_f32_16x16x32_bf16(chf[i][kk], blf[j][kk], acc, 0,0,0);
      acc = __builtin_amdgcn_mfma_f32_16x16x32_bf16(clf[i][kk], bhf[j][kk], acc, 0,0,0);
      acc = __builtin_amdgcn_mfma_f32_16x16x32_bf16(chf[i][kk], bhf[j][kk], acc, 0,0,0);
    }
    g[i][j] = acc;
  }
  // ---- mask -> M, write split-bf16 to sM (C/D->A transform) ----
  float ctt[2][4];
  #pragma unroll
  for (int i=0;i<2;i++)
  #pragma unroll
  for (int r=0;r<4;r++) ctt[i][r] = scum[w][16*i + quad*4 + r];
  #pragma unroll
  for (int j=0;j<2;j++) {
    int s = 16*j + l16;
    float cts = scum[w][s];
    float dts = sdt[w][s];
    #pragma unroll
    for (int i=0;i<2;i++)
    #pragma unroll
    for (int r=0;r<4;r++) {
      int t = 16*i + quad*4 + r;
      float mv = (s <= t) ? g[i][j][r] * __expf(A*(ctt[i][r]-cts)) * dts : 0.f;
      u16 hh, ll; splitbf(mv, hh, ll);
      sMh[w][t*40 + s] = hh;
      sMl[w][t*40 + s] = ll;
    }
  }
  // ---- X^T fragments (reused as Y1-W and S-A) ----
  bf16x8 xhf[4], xlf[4];
  const float* xp = xconv + (size_t)(base_row + quad*8)*1024 + h*64 + l16;
  #pragma unroll
  for (int jp=0;jp<4;jp++) split8s(xp + 16*jp, 1024, xhf[jp], xlf[jp]);
  // ---- Y1 = M @ X ----
  bf16x8 mhf[2], mlf[2];
  #pragma unroll
  for (int i=0;i<2;i++) {
    mhf[i] = *(const bf16x8*)&sMh[w][(16*i + l16)*40 + quad*8];
    mlf[i] = *(const bf16x8*)&sMl[w][(16*i + l16)*40 + quad*8];
  }
  #pragma unroll
  for (int i=0;i<2;i++)
  #pragma unroll
  for (int jp=0;jp<4;jp++) {
    f32x4 acc = {};
    acc = __builtin_amdgcn_mfma_f32_16x16x32_bf16(mhf[i], xlf[jp], acc, 0,0,0);
    acc = __builtin_amdgcn_mfma_f32_16x16x32_bf16(mlf[i], xhf[jp], acc, 0,0,0);
    acc = __builtin_amdgcn_mfma_f32_16x16x32_bf16(mhf[i], xhf[jp], acc, 0,0,0);
    #pragma unroll
    for (int r=0;r<4;r++)
      yraw[(size_t)(base_row + 16*i + quad*4 + r)*1024 + h*64 + 16*jp + l16] = acc[r];
  }
  // ---- S^T = X^T @ (w.B)^T, stored S[inst][p][n] ----
  float wv[8];
  float ct31 = scum[w][31];
  #pragma unroll
  for (int jj=0;jj<8;jj++) {
    int s = quad*8 + jj;
    wv[jj] = sdt[w][s] * __expf(A*(ct31 - scum[w][s]));
  }
  bf16x8 wbh[4], wbl[4];
  #pragma unroll
  for (int j2=0;j2<4;j2++) {
    u16x8 hu, lu; u16 hh, ll;
    #pragma unroll
    for (int jj=0;jj<8;jj++) {
      float b = Bc[(size_t)(base_row + quad*8 + jj)*64 + 16*j2 + l16];
      splitbf(wv[jj]*b, hh, ll); hu[jj]=hh; lu[jj]=ll;
    }
    wbh[j2] = __builtin_bit_cast(bf16x8, hu);
    wbl[j2] = __builtin_bit_cast(bf16x8, lu);
  }
  size_t inst = ((size_t)(dirb*16+h)*NCH + chunk)*4096;
  #pragma unroll
  for (int mp=0;mp<4;mp++)
  #pragma unroll
  for (int j2=0;j2<4;j2++) {
    f32x4 acc = {};
    acc = __builtin_amdgcn_mfma_f32_16x16x32_bf16(xhf[mp], wbl[j2], acc, 0,0,0);
    acc = __builtin_amdgcn_mfma_f32_16x16x32_bf16(xlf[mp], wbh[j2], acc, 0,0,0);
    acc = __builtin_amdgcn_mfma_f32_16x16x32_bf16(xhf[mp], wbh[j2], acc, 0,0,0);
    #pragma unroll
    for (int r=0;r<4;r++)
      S[inst + (size_t)(16*mp + quad*4 + r)*64 + 16*j2 + l16] = acc[r];
  }
}

// ---------- K4b: inter-chunk combine; S[c] overwritten with h_start(c) ----------
__global__ __launch_bounds__(256) void scan_comb(
  const float* __restrict__ cumdec, float* __restrict__ S)
{
  int ih = blockIdx.x >> 4;            // dirb*16 + h
  int sub = blockIdx.x & 15;
  int dirb = ih >> 4, h = ih & 15;
  int elem = sub*256 + threadIdx.x;    // 0..4095 = p*64+n
  size_t base = (size_t)ih*NCH*4096 + elem;
  float hr = 0.f;
  for (int c=0;c<NCH;c++) {
    float P = cumdec[((size_t)(dirb*1024 + c*CT + CT-1))*16 + h];
    float s = S[base + c*4096];
    S[base + c*4096] = hr;             // h_start for chunk c
    hr = fmaf(hr, P, s);
  }
}

// ---------- K4c: Y2 = a_t * (C @ h0^T) added to yraw (MFMA) ----------
__global__ __launch_bounds__(256) void scan_y2(
  const float* __restrict__ Cc, const float* __restrict__ cumdec,
  const float* __restrict__ S, float* __restrict__ yraw)
{
  int bx = blockIdx.x;
  int hq = bx & 3, chunk = (bx>>2)&(NCH-1), dirb = bx>>7;
  if (chunk == 0) return;               // h_start = 0
  int w = threadIdx.x >> 6, lane = threadIdx.x & 63;
  int h = hq*4 + w;
  int row0 = dirb*1024 + chunk*CT;
  const int quad = lane>>4, l16 = lane&15;
  size_t inst = ((size_t)(dirb*16+h)*NCH + chunk)*4096;
  float at[2][4];
  #pragma unroll
  for (int i=0;i<2;i++)
  #pragma unroll
  for (int r=0;r<4;r++)
    at[i][r] = cumdec[(size_t)(row0 + 16*i + quad*4 + r)*16 + h];
  bf16x8 chf[2][2], clf[2][2];
  #pragma unroll
  for (int i=0;i<2;i++)
  #pragma unroll
  for (int kk=0;kk<2;kk++)
    split8(Cc + (size_t)(row0 + 16*i + l16)*64 + kk*32 + quad*8, chf[i][kk], clf[i][kk]);
  bf16x8 hhf[4][2], hlf[4][2];
  #pragma unroll
  for (int j=0;j<4;j++)
  #pragma unroll
  for (int kk=0;kk<2;kk++)
    split8(S + inst + (size_t)(16*j + l16)*64 + kk*32 + quad*8, hhf[j][kk], hlf[j][kk]);
  #pragma unroll
  for (int i=0;i<2;i++)
  #pragma unroll
  for (int j=0;j<4;j++) {
    f32x4 acc = {};
    #pragma unroll
    for (int kk=0;kk<2;kk++) {
      acc = __builtin_amdgcn_mfma_f32_16x16x32_bf16(chf[i][kk], hlf[j][kk], acc, 0,0,0);
      acc = __builtin_amdgcn_mfma_f32_16x16x32_bf16(clf[i][kk], hhf[j][kk], acc, 0,0,0);
      acc = __builtin_amdgcn_mfma_f32_16x16x32_bf16(chf[i][kk], hhf[j][kk], acc, 0,0,0);
    }
    #pragma unroll
    for (int r=0;r<4;r++) {
      size_t idx = (size_t)(row0 + 16*i + quad*4 + r)*1024 + h*64 + 16*j + l16;
      yraw[idx] += at[i][r]*acc[r];
    }
  }
}

// ---------------- K5: +x*D, gate silu(z), rmsnorm -> yg hi/lo planes ----------------
__global__ __launch_bounds__(256) void gate_norm(
  const float* __restrict__ yraw, const float* __restrict__ xconv,
  const float* __restrict__ Z,
  const float* __restrict__ f_D, const float* __restrict__ b_D,
  const float* __restrict__ f_gw, const float* __restrict__ b_gw,
  u16* __restrict__ ygh, u16* __restrict__ ygl)
{
  int bm = blockIdx.x, tid = threadIdx.x;
  int dir = bm >> 12;
  const float* Dp = dir ? b_D : f_D;
  const float* gw = dir ? b_gw : f_gw;
  int c0 = tid*4;
  float4 y4 = *(const float4*)&yraw [(size_t)bm*DI + c0];
  float4 x4 = *(const float4*)&xconv[(size_t)bm*DI + c0];
  float4 z4 = *(const float4*)&Z[(size_t)bm*DIP + c0];   // z = cols 0..1023
  float Dv = Dp[c0>>6];
  float4 v;
  v.x = (y4.x + x4.x*Dv) * (z4.x * sigm(z4.x));
  v.y = (y4.y + x4.y*Dv) * (z4.y * sigm(z4.y));
  v.z = (y4.z + x4.z*Dv) * (z4.z * sigm(z4.z));
  v.w = (y4.w + x4.w*Dv) * (z4.w * sigm(z4.w));
  float ss = v.x*v.x + v.y*v.y + v.z*v.z + v.w*v.w;
  #pragma unroll
  for (int off=32; off; off>>=1) ss += __shfl_xor(ss, off, 64);
  __shared__ float red[4];
  if ((tid&63)==0) red[tid>>6] = ss;
  __syncthreads();
  float total = red[0]+red[1]+red[2]+red[3];
  float rs = rsqrtf(total*(1.f/1024.f) + 1e-5f);
  float4 g4 = *(const float4*)&gw[c0];
  ushort4 hh, ll;
  splitbf(v.x*rs*g4.x, hh.x, ll.x);
  splitbf(v.y*rs*g4.y, hh.y, ll.y);
  splitbf(v.z*rs*g4.z, hh.z, ll.z);
  splitbf(v.w*rs*g4.w, hh.w, ll.w);
  *(ushort4*)&ygh[(size_t)bm*DI + c0] = hh;
  *(ushort4*)&ygl[(size_t)bm*DI + c0] = ll;
}

extern "C" void kernel_launch(void* const* d_in, const int* in_sizes, int n_in,
                              void* d_out, int out_size, void* d_ws, size_t ws_size,
                              hipStream_t stream)
{
  const float* x        = (const float*)d_in[0];
  const float* norm_w   = (const float*)d_in[1];
  const float* f_in_w   = (const float*)d_in[2];
  const float* f_conv_w = (const float*)d_in[3];
  const float* f_conv_b = (const float*)d_in[4];
  const float* f_dt_bias= (const float*)d_in[5];
  const float* f_A_log  = (const float*)d_in[6];
  const float* f_D      = (const float*)d_in[7];
  const float* f_gw     = (const float*)d_in[8];
  const float* f_out_w  = (const float*)d_in[9];
  const float* b_in_w   = (const float*)d_in[10];
  const float* b_conv_w = (const float*)d_in[11];
  const float* b_conv_b = (const float*)d_in[12];
  const float* b_dt_bias= (const float*)d_in[13];
  const float* b_A_log  = (const float*)d_in[14];
  const float* b_D      = (const float*)d_in[15];
  const float* b_gw     = (const float*)d_in[16];
  const float* b_out_w  = (const float*)d_in[17];
  const float* proj_w   = (const float*)d_in[18];

  char* ws = (char*)d_ws;
  size_t off = 0;
  auto alloc = [&](size_t bytes)->char* {
    char* p = ws + off; off = (off + bytes + 255) & ~(size_t)255; return p;
  };
  constexpr size_t WTOT = 2*(size_t)NIN + 3*(size_t)NOUT;
  u16*   hbh   = (u16*)  alloc((size_t)MR*512*2);
  u16*   hbl   = (u16*)  alloc((size_t)MR*512*2);
  u16*   wH    = (u16*)  alloc(WTOT*2);
  u16*   wL    = (u16*)  alloc(WTOT*2);
  float* Z     = (float*)alloc(2*(size_t)MR*DIP*4);
  float* xconv = (float*)alloc(2*(size_t)MR*DI*4);
  float* Bc    = (float*)alloc(2*(size_t)MR*64*4);
  float* Cc    = (float*)alloc(2*(size_t)MR*64*4);
  float* dtq   = (float*)alloc(2*(size_t)MR*NH*4);
  float* cumdec= (float*)alloc(2*(size_t)MR*NH*4);
  float* S     = (float*)alloc((size_t)4096*4096*4);
  float* yraw  = (float*)alloc(2*(size_t)MR*DI*4);
  u16* wih = wH;                   u16* wil = wL;
  u16* woh = wH + 2*(size_t)NIN;   u16* wol = wL + 2*(size_t)NIN;
  u16* wph = woh + 2*(size_t)NOUT; u16* wpl = wol + 2*(size_t)NOUT;
  // alias late-stage planes into S (dead after scan_y2):
  u16* ycath = (u16*)((char*)S);
  u16* ycatl = (u16*)((char*)S + ((size_t)MR*DI*2));
  u16* ygh   = (u16*)((char*)S + 2*((size_t)MR*DI*2));
  u16* ygl   = (u16*)((char*)S + 4*((size_t)MR*DI*2));

  cast_all<<<(int)((WTOT+255)/256),256,0,stream>>>(f_in_w, b_in_w, f_out_w, b_out_w, proj_w, wH, wL);

  rmsnorm_x<<<MR,256,0,stream>>>(x, norm_w, hbh, hbl);
  gemm_in<<<dim3(32,18,2),256,0,stream>>>(hbh, hbl, wih, wil, Z);
  conv_dt<<<2*MR,320,0,stream>>>(Z, f_conv_w, f_conv_b, b_conv_w, b_conv_b,
                                 f_dt_bias, b_dt_bias, xconv, Bc, Cc, dtq);
  scan_mfma<<<1024,256,0,stream>>>(dtq, xconv, Bc, Cc, f_A_log, b_A_log,
                                   yraw, cumdec, S);
  scan_comb<<<2048,256,0,stream>>>(cumdec, S);
  scan_y2<<<1024,256,0,stream>>>(Cc, cumdec, S, yraw);
  gate_norm<<<2*MR,256,0,stream>>>(yraw, xconv, Z, f_D, b_D, f_gw, b_gw, ygh, ygl);
  gemm_out<1><<<dim3(64,4,2),256,0,stream>>>(ygh, ygl, woh, wol, nullptr, nullptr, ycath, ycatl);
  gemm_out<2><<<dim3(64,4,1),256,0,stream>>>(ycath, ycatl, wph, wpl, (float*)d_out, x, nullptr, nullptr);
}